// Round 7
// baseline (254.833 us; speedup 1.0000x reference)
//
#include <hip/hip_runtime.h>
#include <hip/hip_bf16.h>

#define N_NODES 262144
#define NUM_C   256
#define DIM     128
#define NUM_G   128
#define GMAX    8
#define CHUNK   32        // nodes per pipeline stage
#define NCHUNK  8         // 256 nodes per block

typedef short  bf16x8 __attribute__((ext_vector_type(8)));
typedef float  f32x4  __attribute__((ext_vector_type(4)));

__device__ __forceinline__ short f2b(float f) {
    __hip_bfloat16 h = __float2bfloat16(f);
    return *reinterpret_cast<short*>(&h);
}

// ---------------------------------------------------------------------------
// Prep: zero out, convert W fp32->bf16 (row-major, unpadded), compute c_sq,
// build cum_end[g] from the sorted batch. Grid: 128 x 256. (verified r1/r2)
// ---------------------------------------------------------------------------
__global__ void centroid_prep(const float* __restrict__ W,
                              const int* __restrict__ batch,
                              float* __restrict__ out,
                              short* __restrict__ Wb,
                              float* __restrict__ csq,
                              int* __restrict__ cum_end)
{
    const int t   = threadIdx.x;
    const int b   = blockIdx.x;
    const int gid = b * 256 + t;

    float w = W[gid];
    out[gid] = 0.f;
    Wb[gid] = f2b(w);

    __shared__ float red[256];
    red[t] = w * w;
    __syncthreads();
    for (int off = 64; off > 0; off >>= 1) {
        if ((t & 127) < off) red[t] += red[t + off];
        __syncthreads();
    }
    if (t == 0)   csq[2 * b]     = red[0];
    if (t == 128) csq[2 * b + 1] = red[128];

    long i0 = (long)gid * 8;
    int g = batch[i0];
    if (gid == 0) {
        for (int gg = 0; gg < g; ++gg) cum_end[gg] = 0;
    }
    for (int k = 0; k < 8; ++k) {
        long i = i0 + k;
        int gn = (i + 1 < N_NODES) ? batch[i + 1] : NUM_G;
        if (gn != g) {
            for (int gg = g; gg < gn; ++gg) cum_end[gg] = (int)(i + 1);
        }
        g = gn;
    }
}

// ---------------------------------------------------------------------------
// Main, round-7 restructure.  1024 blocks x 512 threads, 256 nodes/block in
// 8 chunks of 32.  r0-r6 findings: (1) kernel was phase-serialized (load
// burst then compute, HBM duty cycle ~25%); (2) plain loads get remat'd to
// their use point (r6: VGPR 52 proves raw[] never stayed live) so source-
// order pipelining is deleted; (3) B-from-LDS re-reads were ~2nd tallest
// pipe (4 ds_read_b128 per 4-8 MFMA).
// Fixes here:
//  * B IN REGISTERS: 8 waves = 2 node-groups x 4 centroid-quarters; each
//    wave holds B-frags for its 64 centroids (4 ct x 16 VGPR = 64), loaded
//    once from Wb.  W leaves LDS entirely; per-chunk B ds_reads = 0.
//  * x streams through a 2x8KB LDS double-buffer as bf16; per-node xsq
//    computed ONCE at staging (f32, full accuracy), stored in LDS.
//  * stage loads (2 f32x4/thread) issue at phase top and are pinned by
//    asm volatile("" ::: "memory") — loads cannot sink/remat across a
//    memory clobber — then consumed after the compute section.  One
//    barrier per chunk.  HBM stays busy during MFMA/epilogue.
//  * A-rows in LDS XOR-swizzled (^(node&7)<<3 in shorts) on both the
//    ds_write and ds_read side: 256-B rows would be a 16-way conflict.
// __launch_bounds__(512,2): 2 blocks/CU -> 128-VGPR budget (2nd arg =
// blocks/CU, established r1-r3).  Est. live set ~115.
// dist = sqrt(max(xsq + csq - 2*cross, 0)); pooled via wave butterfly ->
// block LDS accumulator -> global atomics; finish divides by counts.
// ---------------------------------------------------------------------------
__global__ __launch_bounds__(512, 2) void centroid_main(
    const float* __restrict__ x,
    const int* __restrict__ batch,
    const short* __restrict__ Wb,
    const float* __restrict__ csq,
    float* __restrict__ out)
{
    __shared__ __align__(16) short xb[2][CHUNK * 128];   // bf16 rows, swizzled; 2x8192 B
    __shared__ __align__(16) float xsq[2][CHUNK];        // 256 B
    __shared__ float lacc[GMAX * NUM_C];                 // 8192 B

    const int t  = threadIdx.x;
    const int nb = blockIdx.x << 8;          // 256 nodes per block

    const int lane = t & 63;
    const int m16  = lane & 15;
    const int quad = lane >> 4;
    const int wid  = t >> 6;                 // 0..7
    const int ng   = wid & 1;                // node-group: 16 nodes
    const int cq   = wid >> 1;               // centroid-quarter: 64 c

    // staging role: thread t stages node sn (of 32), dims sl*8..sl*8+8
    const int sn = t >> 4;                   // 0..31
    const int sl = t & 15;                   // 0..15
    const float* xsrc = x + (long)(nb + sn) * DIM + sl * 8;

    // ---- issue chunk-0 x loads FIRST (latency hidden under setup) ----
    f32x4 ra = *(const f32x4*)(xsrc);
    f32x4 rb = *(const f32x4*)(xsrc + 4);
    asm volatile("" ::: "memory");           // pin loads above this point

    // ---- B fragments: 4 ct-tiles x 4 k-slices, held in 64 VGPRs ----
    bf16x8 b[4][4];
#pragma unroll
    for (int ct = 0; ct < 4; ++ct) {
        const short* wr = Wb + (cq * 64 + ct * 16 + m16) * DIM + quad * 8;
#pragma unroll
        for (int ks = 0; ks < 4; ++ks)
            b[ct][ks] = *(const bf16x8*)(wr + ks * 32);
    }
    float csr[4];
#pragma unroll
    for (int ct = 0; ct < 4; ++ct)
        csr[ct] = csq[cq * 64 + ct * 16 + m16];

    for (int i = t; i < GMAX * NUM_C; i += 512) lacc[i] = 0.f;

    const int  gmin    = batch[nb];
    const int  span    = batch[nb + 255] - gmin + 1;
    const bool use_lds = (span <= GMAX);

    // ---- stage chunk 0 into buf 0 (cvt waits on ra/rb here) ----
    {
        float ss = 0.f;
        bf16x8 pk;
#pragma unroll
        for (int j = 0; j < 4; ++j) {
            ss += ra[j] * ra[j] + rb[j] * rb[j];
            pk[j]     = f2b(ra[j]);
            pk[j + 4] = f2b(rb[j]);
        }
        ss += __shfl_xor(ss, 1);
        ss += __shfl_xor(ss, 2);
        ss += __shfl_xor(ss, 4);
        ss += __shfl_xor(ss, 8);
        if (sl == 0) xsq[0][sn] = ss;
        *(bf16x8*)&xb[0][sn * 128 + ((sl * 8) ^ ((sn & 7) << 3))] = pk;
    }
    __syncthreads();

    // ---- chunk loop: compute k from buf, stage k+1 into buf^1 ----
    for (int k = 0; k < NCHUNK; ++k) {
        const int buf = k & 1;

        if (k + 1 < NCHUNK) {
            const float* xp = xsrc + (long)(k + 1) * CHUNK * DIM;
            ra = *(const f32x4*)(xp);
            rb = *(const f32x4*)(xp + 4);
            asm volatile("" ::: "memory");   // loads stay issued here, in
        }                                    // flight through the compute

        // ---- compute chunk k ----
        {
            const int node = ng * 16 + m16;  // A-row this lane holds
            bf16x8 af[4];
#pragma unroll
            for (int ks = 0; ks < 4; ++ks)
                af[ks] = *(const bf16x8*)&xb[buf][node * 128 +
                          ((ks * 32 + quad * 8) ^ ((node & 7) << 3))];
            const f32x4 pre4 = *(const f32x4*)&xsq[buf][ng * 16 + quad * 4];

            const int bn  = nb + k * CHUNK + ng * 16;
            const int g0  = batch[bn];
            const bool uni = (g0 == batch[bn + 15]);

#pragma unroll
            for (int ct = 0; ct < 4; ++ct) {
                f32x4 acc = {0.f, 0.f, 0.f, 0.f};
                acc = __builtin_amdgcn_mfma_f32_16x16x32_bf16(af[0], b[ct][0], acc, 0, 0, 0);
                acc = __builtin_amdgcn_mfma_f32_16x16x32_bf16(af[1], b[ct][1], acc, 0, 0, 0);
                acc = __builtin_amdgcn_mfma_f32_16x16x32_bf16(af[2], b[ct][2], acc, 0, 0, 0);
                acc = __builtin_amdgcn_mfma_f32_16x16x32_bf16(af[3], b[ct][3], acc, 0, 0, 0);

                const int   c  = cq * 64 + ct * 16 + m16;
                const float cs = csr[ct];

                if (use_lds && uni) {
                    float v = 0.f;
#pragma unroll
                    for (int r = 0; r < 4; ++r) {
                        float d2 = __builtin_fmaf(acc[r], -2.f, pre4[r] + cs);
                        v += __builtin_amdgcn_sqrtf(__builtin_fmaxf(d2, 0.f));
                    }
                    v += __shfl_xor(v, 16);
                    v += __shfl_xor(v, 32);
                    if (quad == 0)
                        atomicAdd(&lacc[(g0 - gmin) * NUM_C + c], v);
                } else {
#pragma unroll
                    for (int r = 0; r < 4; ++r) {
                        float d2 = __builtin_fmaf(acc[r], -2.f, pre4[r] + cs);
                        float d  = __builtin_amdgcn_sqrtf(__builtin_fmaxf(d2, 0.f));
                        int   g  = uni ? g0 : batch[bn + quad * 4 + r];
                        if (use_lds) atomicAdd(&lacc[(g - gmin) * NUM_C + c], d);
                        else         atomicAdd(&out[g * NUM_C + c], d);
                    }
                }
            }
        }

        // ---- write chunk k+1 (loads consumed here, after compute) ----
        if (k + 1 < NCHUNK) {
            float ss = 0.f;
            bf16x8 pk;
#pragma unroll
            for (int j = 0; j < 4; ++j) {
                ss += ra[j] * ra[j] + rb[j] * rb[j];
                pk[j]     = f2b(ra[j]);
                pk[j + 4] = f2b(rb[j]);
            }
            ss += __shfl_xor(ss, 1);
            ss += __shfl_xor(ss, 2);
            ss += __shfl_xor(ss, 4);
            ss += __shfl_xor(ss, 8);
            if (sl == 0) xsq[buf ^ 1][sn] = ss;
            *(bf16x8*)&xb[buf ^ 1][sn * 128 + ((sl * 8) ^ ((sn & 7) << 3))] = pk;
        }
        __syncthreads();
    }

    if (use_lds) {
        for (int i = t; i < span * NUM_C; i += 512)
            atomicAdd(&out[(gmin + (i >> 8)) * NUM_C + (i & 255)], lacc[i]);
    }
}

// ---------------------------------------------------------------------------
// Finish: divide sums by per-graph counts. Grid: 128 x 256.
// ---------------------------------------------------------------------------
__global__ void centroid_finish(float* __restrict__ out,
                                const int* __restrict__ cum_end)
{
    const int g = blockIdx.x;
    const int c = threadIdx.x;
    int cnt = cum_end[g] - (g ? cum_end[g - 1] : 0);
    float denom = (float)(cnt > 0 ? cnt : 1);
    out[g * NUM_C + c] /= denom;
}

extern "C" void kernel_launch(void* const* d_in, const int* in_sizes, int n_in,
                              void* d_out, int out_size, void* d_ws, size_t ws_size,
                              hipStream_t stream) {
    const float* x     = (const float*)d_in[0];
    const int*   batch = (const int*)d_in[1];
    const float* W     = (const float*)d_in[2];
    float*       out   = (float*)d_out;

    // workspace: Wb (64 KB) | csq (1 KB) | cum_end (512 B)
    short* Wb      = (short*)d_ws;
    float* csq     = (float*)((char*)d_ws + 65536);
    int*   cum_end = (int*)((char*)d_ws + 65536 + 1024);

    centroid_prep<<<128, 256, 0, stream>>>(W, batch, out, Wb, csq, cum_end);
    centroid_main<<<N_NODES / 256, 512, 0, stream>>>(x, batch, Wb, csq, out);
    centroid_finish<<<NUM_G, 256, 0, stream>>>(out, cum_end);
}

// Round 8
// 225.668 us; speedup vs baseline: 1.1292x; 1.1292x over previous
//
#include <hip/hip_runtime.h>
#include <hip/hip_bf16.h>

#define N_NODES 262144
#define NUM_C   256
#define DIM     128
#define NUM_G   128
#define GMAX    8
#define WPAD    136   // padded LDS row stride in shorts (272 B, 16B-aligned)

typedef short  bf16x8 __attribute__((ext_vector_type(8)));
typedef float  f32x4  __attribute__((ext_vector_type(4)));

__device__ __forceinline__ short f2b(float f) {
    __hip_bfloat16 h = __float2bfloat16(f);
    return *reinterpret_cast<short*>(&h);
}

// inline-asm global load: cannot be remat'd/sunk (volatile), pairs with the
// counted vmcnt below.  offset imm is a string literal (13-bit signed ok).
#define GLD(dst, p, imm) \
    asm volatile("global_load_dwordx4 %0, %1, off offset:" imm \
                 : "=v"(dst) : "v"(p))

#define ISSUE(B, p) do {                                   \
    GLD(B[0], (p), "0");   GLD(B[1], (p), "16");           \
    GLD(B[2], (p), "128"); GLD(B[3], (p), "144");          \
    GLD(B[4], (p), "256"); GLD(B[5], (p), "272");          \
    GLD(B[6], (p), "384"); GLD(B[7], (p), "400"); } while (0)

// counted wait: tile t's 8 loads retired, tile t+1's 8 stay in flight.
// sched_barrier(0) fences VALU hoisting across the wait (guide lesson #18).
#define WAITV8() do { asm volatile("s_waitcnt vmcnt(8)" ::: "memory"); \
                      __builtin_amdgcn_sched_barrier(0); } while (0)
#define WAITV0() do { asm volatile("s_waitcnt vmcnt(0)" ::: "memory"); \
                      __builtin_amdgcn_sched_barrier(0); } while (0)

// ---------------------------------------------------------------------------
// Prep: zero out, convert W fp32->bf16 (row-major, unpadded), compute c_sq,
// build cum_end[g] from the sorted batch. Grid: 128 x 256. (verified r1/r2)
// ---------------------------------------------------------------------------
__global__ void centroid_prep(const float* __restrict__ W,
                              const int* __restrict__ batch,
                              float* __restrict__ out,
                              short* __restrict__ Wb,
                              float* __restrict__ csq,
                              int* __restrict__ cum_end)
{
    const int t   = threadIdx.x;
    const int b   = blockIdx.x;
    const int gid = b * 256 + t;

    float w = W[gid];
    out[gid] = 0.f;
    Wb[gid] = f2b(w);

    __shared__ float red[256];
    red[t] = w * w;
    __syncthreads();
    for (int off = 64; off > 0; off >>= 1) {
        if ((t & 127) < off) red[t] += red[t + off];
        __syncthreads();
    }
    if (t == 0)   csq[2 * b]     = red[0];
    if (t == 128) csq[2 * b + 1] = red[128];

    long i0 = (long)gid * 8;
    int g = batch[i0];
    if (gid == 0) {
        for (int gg = 0; gg < g; ++gg) cum_end[gg] = 0;
    }
    for (int k = 0; k < 8; ++k) {
        long i = i0 + k;
        int gn = (i + 1 < N_NODES) ? batch[i + 1] : NUM_G;
        if (gn != g) {
            for (int gg = g; gg < gn; ++gg) cum_end[gg] = (int)(i + 1);
        }
        g = gn;
    }
}

// ---------------------------------------------------------------------------
// Main, round-8: 512 blocks x 512 threads, one generation (2 blocks/CU).
// r0 skeleton (whole-W padded LDS, per-wave 16-node A-tiles, same ct-loop &
// epilogue) but each wave streams FOUR tiles with a hand-held register
// pipeline: tile t+1's 8 x global_load_dwordx4 are issued via inline asm
// (can't be remat'd/sunk — r6 showed plain loads get remat'd to use point)
// and waited with counted s_waitcnt vmcnt(8) (never 0 mid-stream), so 8 KB
// per wave is in flight through every ct-loop.  NO mid-stream barriers
// (r7's per-chunk __syncthreads re-locked wave phases).  All batch meta is
// preloaded before the pipeline so no compiler VMEM (with its conservative
// vmcnt(0)) lands inside the loop.  Memory flows continuously -> duty-cycle
// fix for the 80us plateau (134MB @ ~1.7TB/s effective, all pipes <25%).
// __launch_bounds__(512,2): 128-VGPR budget (2nd arg = blocks/CU, r1-r3);
// est. live ~105.  dist = sqrt(max(xsq + csq - 2*cross, 0)); pooled via
// wave butterfly -> block LDS accumulator -> global atomics.
// ---------------------------------------------------------------------------
__global__ __launch_bounds__(512, 2) void centroid_main(
    const float* __restrict__ x,
    const int* __restrict__ batch,
    const short* __restrict__ Wb,
    const float* __restrict__ csq,
    float* __restrict__ out)
{
    __shared__ short wlds[NUM_C * WPAD];      // 69632 B
    __shared__ float lacc[GMAX * NUM_C];      //  8192 B
    __shared__ float csq_l[NUM_C];            //  1024 B

    const int t  = threadIdx.x;
    const int nb = blockIdx.x << 9;           // 512 nodes per block

    // ---- stage whole W (bf16) into padded LDS, coalesced global reads ----
#pragma unroll
    for (int i = 0; i < 8; ++i) {
        int k = i * 512 + t;                  // chunk of 8 shorts, 4096 total
        bf16x8 v = *(const bf16x8*)(Wb + k * 8);
        *(bf16x8*)(wlds + (k >> 4) * WPAD + (k & 15) * 8) = v;
    }
    if (t < NUM_C) csq_l[t] = csq[t];
#pragma unroll
    for (int i = t; i < GMAX * NUM_C; i += 512) lacc[i] = 0.f;

    const int  gmin    = batch[nb];
    const int  span    = batch[nb + 511] - gmin + 1;
    const bool use_lds = (span <= GMAX);

    const int lane = t & 63;
    const int m16  = lane & 15;
    const int quad = lane >> 4;
    const int wid  = t >> 6;                  // wave id 0..7
    const int nbw  = nb + wid * 64;           // wave's 64 nodes (4 tiles x 16)

    // ---- preload ALL batch meta (keeps compiler VMEM out of the loop) ----
    int  g0m[4];
    bool unim[4];
#pragma unroll
    for (int tt = 0; tt < 4; ++tt) {
        g0m[tt]  = batch[nbw + tt * 16];
        unim[tt] = (g0m[tt] == batch[nbw + tt * 16 + 15]);
    }

    // lane's base pointer into its node row: node nbw+m16, dims quad*8..
    const float* xw = x + (long)(nbw + m16) * DIM + quad * 8;

    // ---- prologue: issue tile0 (drained by the barrier, that's fine) ----
    f32x4 bk[2][8];
    ISSUE(bk[0], xw);

    __syncthreads();   // W staging + lacc init visible (drains tile0 loads)

    // ---- 4-tile stream: compute tile t while tile t+1 flies ----
#pragma unroll
    for (int tl = 0; tl < 4; ++tl) {
        if (tl < 3) {
            const float* pn = xw + (tl + 1) * (16 * DIM);
            ISSUE(bk[(tl + 1) & 1], pn);
        }
        if (tl < 3) WAITV8(); else WAITV0();

        // convert tile tl -> A fragments + row sum-of-squares
        bf16x8 af[4];
        float  pre[4];
        {
            float ss = 0.f;
#pragma unroll
            for (int ks = 0; ks < 4; ++ks) {
                f32x4 u0 = bk[tl & 1][2 * ks];
                f32x4 u1 = bk[tl & 1][2 * ks + 1];
                bf16x8 av;
#pragma unroll
                for (int j = 0; j < 4; ++j) {
                    ss += u0[j] * u0[j] + u1[j] * u1[j];
                    av[j]     = f2b(u0[j]);
                    av[j + 4] = f2b(u1[j]);
                }
                af[ks] = av;
            }
            ss += __shfl_xor(ss, 16);
            ss += __shfl_xor(ss, 32);
#pragma unroll
            for (int r = 0; r < 4; ++r) pre[r] = __shfl(ss, quad * 4 + r);
        }

        const int  bn  = nbw + tl * 16;
        const int  g0  = g0m[tl];
        const bool uni = unim[tl];

        // ---- column-tile loop: B from LDS (r0-verified) ----
#pragma unroll 2
        for (int ct = 0; ct < 16; ++ct) {
            const int c = ct * 16 + m16;
            const short* wp = wlds + c * WPAD + quad * 8;
            bf16x8 b0 = *(const bf16x8*)(wp);
            bf16x8 b1 = *(const bf16x8*)(wp + 32);
            bf16x8 b2 = *(const bf16x8*)(wp + 64);
            bf16x8 b3 = *(const bf16x8*)(wp + 96);
            const float cs = csq_l[c];

            f32x4 acc = {0.f, 0.f, 0.f, 0.f};
            acc = __builtin_amdgcn_mfma_f32_16x16x32_bf16(af[0], b0, acc, 0, 0, 0);
            acc = __builtin_amdgcn_mfma_f32_16x16x32_bf16(af[1], b1, acc, 0, 0, 0);
            acc = __builtin_amdgcn_mfma_f32_16x16x32_bf16(af[2], b2, acc, 0, 0, 0);
            acc = __builtin_amdgcn_mfma_f32_16x16x32_bf16(af[3], b3, acc, 0, 0, 0);

            if (use_lds && uni) {
                float v = 0.f;
#pragma unroll
                for (int r = 0; r < 4; ++r) {
                    float d2 = __builtin_fmaf(acc[r], -2.f, pre[r] + cs);
                    v += __builtin_amdgcn_sqrtf(__builtin_fmaxf(d2, 0.f));
                }
                v += __shfl_xor(v, 16);
                v += __shfl_xor(v, 32);
                if (quad == 0)
                    atomicAdd(&lacc[(g0 - gmin) * NUM_C + c], v);
            } else {
#pragma unroll
                for (int r = 0; r < 4; ++r) {
                    float d2 = __builtin_fmaf(acc[r], -2.f, pre[r] + cs);
                    float d  = __builtin_amdgcn_sqrtf(__builtin_fmaxf(d2, 0.f));
                    int   g  = uni ? g0 : batch[bn + quad * 4 + r];
                    if (use_lds) atomicAdd(&lacc[(g - gmin) * NUM_C + c], d);
                    else         atomicAdd(&out[g * NUM_C + c], d);
                }
            }
        }
    }

    __syncthreads();
    if (use_lds) {
        for (int i = t; i < span * NUM_C; i += 512)
            atomicAdd(&out[(gmin + (i >> 8)) * NUM_C + (i & 255)], lacc[i]);
    }
}

// ---------------------------------------------------------------------------
// Finish: divide sums by per-graph counts. Grid: 128 x 256.
// ---------------------------------------------------------------------------
__global__ void centroid_finish(float* __restrict__ out,
                                const int* __restrict__ cum_end)
{
    const int g = blockIdx.x;
    const int c = threadIdx.x;
    int cnt = cum_end[g] - (g ? cum_end[g - 1] : 0);
    float denom = (float)(cnt > 0 ? cnt : 1);
    out[g * NUM_C + c] /= denom;
}

extern "C" void kernel_launch(void* const* d_in, const int* in_sizes, int n_in,
                              void* d_out, int out_size, void* d_ws, size_t ws_size,
                              hipStream_t stream) {
    const float* x     = (const float*)d_in[0];
    const int*   batch = (const int*)d_in[1];
    const float* W     = (const float*)d_in[2];
    float*       out   = (float*)d_out;

    // workspace: Wb (64 KB) | csq (1 KB) | cum_end (512 B)
    short* Wb      = (short*)d_ws;
    float* csq     = (float*)((char*)d_ws + 65536);
    int*   cum_end = (int*)((char*)d_ws + 65536 + 1024);

    centroid_prep<<<128, 256, 0, stream>>>(W, batch, out, Wb, csq, cum_end);
    centroid_main<<<N_NODES / 512, 512, 0, stream>>>(x, batch, Wb, csq, out);
    centroid_finish<<<NUM_G, 256, 0, stream>>>(out, cum_end);
}